// Round 1
// baseline (2232.195 us; speedup 1.0000x reference)
//
#include <hip/hip_runtime.h>
#include <cstdint>
#include <cstddef>

#define B_  64
#define T_  512
#define I_  512
#define H_  1024

typedef float  f32x4  __attribute__((ext_vector_type(4)));
typedef __bf16 bf16x8 __attribute__((ext_vector_type(8)));
typedef unsigned short us4v __attribute__((ext_vector_type(4)));
typedef unsigned int  u32x4 __attribute__((ext_vector_type(4)));
typedef unsigned long long ull;

__device__ __forceinline__ unsigned short f2bf(float f) {
  unsigned int u = __float_as_uint(f);
  u = (u + 0x7fffu + ((u >> 16) & 1u)) >> 16;   // round-to-nearest-even
  return (unsigned short)u;
}

__device__ __forceinline__ float fast_tanh(float x) {
  x = fminf(10.f, fmaxf(-10.f, x));
  float e = __expf(2.f * x);
  return (e - 1.f) * __builtin_amdgcn_rcpf(e + 1.f);
}

// Relaxed agent-scope atomics: coherent at the device coherence point,
// no cache-maintenance instructions, bypass stale per-XCD caching.
__device__ __forceinline__ void st_ag64(ull* p, ull v) {
  __hip_atomic_store(p, v, __ATOMIC_RELAXED, __HIP_MEMORY_SCOPE_AGENT);
}
__device__ __forceinline__ ull ld_ag64(const ull* p) {
  return __hip_atomic_load(p, __ATOMIC_RELAXED, __HIP_MEMORY_SCOPE_AGENT);
}

// ---------------------------------------------------------------------------
// Transpose fp32 [R][C] -> bf16 [C][R] (K-major layouts for MFMA B-operands)
// ---------------------------------------------------------------------------
__global__ __launch_bounds__(256) void k_transpose_cvt(
    const float* __restrict__ in, unsigned short* __restrict__ out, int R, int C) {
  __shared__ float tile[64][65];
  const int tx = threadIdx.x & 63, ty = threadIdx.x >> 6;
  const int c0 = blockIdx.x * 64, r0 = blockIdx.y * 64;
#pragma unroll
  for (int i = 0; i < 16; i++) {
    int r = i * 4 + ty;
    tile[r][tx] = in[(size_t)(r0 + r) * C + c0 + tx];
  }
  __syncthreads();
#pragma unroll
  for (int i = 0; i < 16; i++) {
    int c = i * 4 + ty;
    out[(size_t)(c0 + c) * R + r0 + tx] = f2bf(tile[tx][c]);
  }
}

// ---------------------------------------------------------------------------
// bias = b_ih + b_hh  (tagged hbuf needs NO init: 0xAA poison is never a tag)
// ---------------------------------------------------------------------------
__global__ __launch_bounds__(256) void k_prep(
    const float* __restrict__ bih, const float* __restrict__ bhh,
    float* __restrict__ bias) {
  int gid = blockIdx.x * 256 + threadIdx.x;
  if (gid < H_) bias[gid] = bih[gid] + bhh[gid];
}

// ---------------------------------------------------------------------------
// Phase 1: xw = x @ w_ih + bias  -> written into d_out's hidden_seq region
// ---------------------------------------------------------------------------
__global__ __launch_bounds__(256) void k_gemm_xw(
    const float* __restrict__ x, const unsigned short* __restrict__ wihT,
    const float* __restrict__ bias, float* __restrict__ out) {
  __shared__ __align__(16) unsigned short As[128 * 40];
  __shared__ __align__(16) unsigned short Bs[128 * 40];

  const int tid = threadIdx.x;
  const int tileM = blockIdx.x >> 3;
  const int tileN = blockIdx.x & 7;
  const int wv = tid >> 6, lane = tid & 63;
  const int row16 = lane & 15, quad = lane >> 4;
  const int m0 = (wv & 1) * 64, n0 = (wv >> 1) * 64;

  f32x4 acc[4][4];
#pragma unroll
  for (int i = 0; i < 4; i++)
#pragma unroll
    for (int j = 0; j < 4; j++) acc[i][j] = (f32x4){0.f, 0.f, 0.f, 0.f};

  const int ar = tid >> 3, ac = (tid & 7) << 2;
  const int br = tid >> 2, bc = (tid & 3) << 3;

#pragma unroll 1
  for (int kt = 0; kt < I_ / 32; kt++) {
    const int k0 = kt * 32;
#pragma unroll
    for (int i = 0; i < 4; i++) {
      int r = ar + i * 32;
      float4 v = *(const float4*)(x + (size_t)(tileM * 128 + r) * I_ + k0 + ac);
      us4v o;
      o.x = f2bf(v.x); o.y = f2bf(v.y); o.z = f2bf(v.z); o.w = f2bf(v.w);
      *(us4v*)(As + r * 40 + ac) = o;
    }
#pragma unroll
    for (int i = 0; i < 2; i++) {
      int r = br + i * 64;
      *(uint4*)(Bs + r * 40 + bc) =
          *(const uint4*)(wihT + (size_t)(tileN * 128 + r) * I_ + k0 + bc);
    }
    __syncthreads();

    bf16x8 af[4], bfr[4];
#pragma unroll
    for (int mt = 0; mt < 4; mt++)
      af[mt] = *(const bf16x8*)(As + (m0 + mt * 16 + row16) * 40 + quad * 8);
#pragma unroll
    for (int nt = 0; nt < 4; nt++)
      bfr[nt] = *(const bf16x8*)(Bs + (n0 + nt * 16 + row16) * 40 + quad * 8);
#pragma unroll
    for (int mt = 0; mt < 4; mt++)
#pragma unroll
      for (int nt = 0; nt < 4; nt++)
        acc[mt][nt] = __builtin_amdgcn_mfma_f32_16x16x32_bf16(
            af[mt], bfr[nt], acc[mt][nt], 0, 0, 0);
    __syncthreads();
  }

#pragma unroll
  for (int mt = 0; mt < 4; mt++)
#pragma unroll
    for (int nt = 0; nt < 4; nt++) {
      int gc = tileN * 128 + n0 + nt * 16 + row16;
      float bv = bias[gc];
#pragma unroll
      for (int r = 0; r < 4; r++) {
        int gr = tileM * 128 + m0 + mt * 16 + quad * 4 + r;
        out[(size_t)gr * H_ + gc] = acc[mt][nt][r] + bv;
      }
    }
}

// ---------------------------------------------------------------------------
// Phase 2: persistent recurrence with DATA-IS-FLAG message passing.
// 32 blocks x 512 threads = 4 groups(16 batches) x 8 column-chunks(128 cols).
// w_hh column fragments stationary in registers (128 VGPRs/lane).
//
// Why 512 threads: with 256-thread blocks the kernel allocated 156 VGPRs
// (1 block/CU at 4 waves), leaving ~10 spare regs for the 32-word poll ->
// the compiler serialized the poll loads into ~6 latency waves (~1.7us of
// pure spin per step). At 512 threads / __launch_bounds__(512,2) the budget
// is 256 VGPRs/lane; each thread polls only 16 words (32 dest regs), so the
// whole poll issues as ONE parallel latency wave. Groups shrink from 16 to
// 8 producer blocks -> fewer stragglers gating each step.
//
// h exchange: tagged 8B words { hi32 = tag = t+1, lo32 = 2 x bf16 }.
// Single-copy atomicity of the 8B store means tag+payload arrive together:
// NO waitcnt, NO flag array, NO separate flag round trip. Consumers poll
// the data words until all tags match. 0xAA ws poison is never a valid tag.
// Ping-pong parity slots; safety: producer can only reach step t+2 (slot
// reuse) after consuming everyone's t+1 data, which implies everyone
// consumed t's data.
//
// Word w = b*512 + colpair. Thread tid owns words { i*512 + tid }, i.e.
// dword `tid` of every batch row i -> LDS broadcast is lw[i*516+tid]
// (coalesced global, conflict-free LDS). ONE __syncthreads, then each wave
// reads A-fragments with ds_read_b128. hidden_seq stores + next-xw prefetch
// sit after the publish (off-path).
// ---------------------------------------------------------------------------
__global__ __launch_bounds__(512, 2) void k_scan(
    const unsigned short* __restrict__ whhT,
    unsigned short* __restrict__ hbuf,
    float* __restrict__ out) {
  const int bid = blockIdx.x;
  const int g = bid >> 3, j = bid & 7;
  const int tid = threadIdx.x;
  const int wv = tid >> 6, lane = tid & 63;
  const int row = lane & 15, quad = lane >> 4;
  const int bsl = g * 16;                       // batch slice base
  const int mycol = j * 128 + wv * 16 + row;    // this lane's output column

  // tagged h: [group(4)][parity(2)][8192 words] ull
  ull* hb = (ull*)hbuf;
  ull* gbase = hb + g * 16384;

  // LDS payload broadcast: 2 buffers x 16 rows x 516 u32 (pad 512->516)
  __shared__ __align__(16) unsigned int ldsb[2 * 16 * 516];

  // stationary B-operand: whh[k][mycol], K-major, 32 chunks of K=32
  bf16x8 wfrag[32];
  {
    const unsigned short* wp = whhT + (size_t)mycol * H_ + quad * 8;
#pragma unroll
    for (int kk = 0; kk < 32; kk++)
      wfrag[kk] = *(const bf16x8*)(wp + kk * 32);
  }

  // xw prefetch for t=0
  float xwv[4];
  size_t oi[4];
#pragma unroll
  for (int r = 0; r < 4; r++) {
    int b = bsl + quad * 4 + r;
    oi[r] = ((size_t)b * T_) * H_ + mycol;
    xwv[r] = out[oi[r]];
  }

  for (int t = 0; t < T_; ++t) {
    f32x4 acc[4];
#pragma unroll
    for (int c = 0; c < 4; c++) acc[c] = (f32x4){0.f, 0.f, 0.f, 0.f};

    if (t > 0) {
      // --- cooperative tagged load: thread owns words { i*512 + tid } ---
      const ull* src = gbase + ((t - 1) & 1) * 8192 + tid;
      const unsigned int expect = (unsigned int)t;
      ull q[16];
      unsigned int bad;
      do {
#pragma unroll
        for (int i = 0; i < 16; i++) q[i] = ld_ag64(src + i * 512);
        bad = 0u;
#pragma unroll
        for (int i = 0; i < 16; i++)
          bad |= ((unsigned int)(q[i] >> 32)) ^ expect;
      } while (__builtin_expect(bad != 0, 0));

      // --- LDS broadcast: word i*512+tid = (batch i, dword tid) ---
      unsigned int* lw = ldsb + (t & 1) * (16 * 516);
#pragma unroll
      for (int i = 0; i < 16; i++)
        lw[i * 516 + tid] = (unsigned int)q[i];
      __syncthreads();

      // --- MFMA from LDS A-fragments ---
      const unsigned int* ap = lw + row * 516 + quad * 4;
#pragma unroll
      for (int kb = 0; kb < 32; kb++) {
        u32x4 w = *(const u32x4*)(ap + kb * 16);     // ds_read_b128
        bf16x8 a = __builtin_bit_cast(bf16x8, w);
        acc[kb & 3] = __builtin_amdgcn_mfma_f32_16x16x32_bf16(
            a, wfrag[kb], acc[kb & 3], 0, 0, 0);
      }
    }
    f32x4 accf = (acc[0] + acc[1]) + (acc[2] + acc[3]);

    // h = tanh(acc + xw); publish tagged bf16 pairs (8B, tag rides along)
    float hv[4];
    ull* dst = gbase + (t & 1) * 8192;
    const ull tagbits = ((ull)(unsigned int)(t + 1)) << 32;
#pragma unroll
    for (int r = 0; r < 4; r++) {
      float h = fast_tanh(accf[r] + xwv[r]);
      hv[r] = h;
      unsigned int myu = (unsigned int)f2bf(h);
      unsigned int pr  = __shfl_xor(myu, 1);
      unsigned int pair = myu | (pr << 16);          // valid on even lanes
      if ((lane & 1) == 0) {
        int b = quad * 4 + r;
        st_ag64(dst + b * 512 + (mycol >> 1), tagbits | (ull)pair);
      }
    }
    __builtin_amdgcn_sched_barrier(0);   // publish issues before out[] I/O

    // off-critical-path: hidden_seq stores, h_T tail, next xw prefetch
#pragma unroll
    for (int r = 0; r < 4; r++) {
      out[oi[r]] = hv[r];
      if (t == T_ - 1) {
        int b = bsl + quad * 4 + r;
        out[(size_t)B_ * T_ * H_ + (size_t)b * H_ + mycol] = hv[r];
      }
    }
    if (t + 1 < T_) {
#pragma unroll
      for (int r = 0; r < 4; r++) {
        oi[r] += H_;                 // (b*T + t+1)*H + mycol
        xwv[r] = out[oi[r]];
      }
    }
  }
}

// ---------------------------------------------------------------------------
extern "C" void kernel_launch(void* const* d_in, const int* in_sizes, int n_in,
                              void* d_out, int out_size, void* d_ws, size_t ws_size,
                              hipStream_t stream) {
  const float* x    = (const float*)d_in[0];
  const float* w_ih = (const float*)d_in[1];
  const float* w_hh = (const float*)d_in[2];
  const float* b_ih = (const float*)d_in[3];
  const float* b_hh = (const float*)d_in[4];
  float* out = (float*)d_out;

  char* ws = (char*)d_ws;
  unsigned short* whhT = (unsigned short*)(ws);                       // 2 MB
  unsigned short* wihT = (unsigned short*)(ws + (2u << 20));          // 1 MB
  float*          bias = (float*)(ws + (3u << 20));                   // 4 KB
  unsigned short* hbuf = (unsigned short*)(ws + (3u << 20) + 4096);   // 512 KB tagged

  hipLaunchKernelGGL(k_transpose_cvt, dim3(H_ / 64, H_ / 64), dim3(256), 0, stream,
                     w_hh, whhT, H_, H_);
  hipLaunchKernelGGL(k_transpose_cvt, dim3(H_ / 64, I_ / 64), dim3(256), 0, stream,
                     w_ih, wihT, I_, H_);
  hipLaunchKernelGGL(k_prep, dim3(4), dim3(256), 0, stream, b_ih, b_hh, bias);
  hipLaunchKernelGGL(k_gemm_xw, dim3((B_ * T_ / 128) * (H_ / 128)), dim3(256), 0,
                     stream, x, wihT, bias, out);
  hipLaunchKernelGGL(k_scan, dim3(32), dim3(512), 0, stream, whhT, hbuf, out);
}